// Round 5
// baseline (242.118 us; speedup 1.0000x reference)
//
#include <hip/hip_runtime.h>

#define BATCH 8192
#define DIM 1024
#define HEADS 8
#define HEAD_DIM 128
#define DSTATE 256

typedef __attribute__((ext_vector_type(8))) short short8v;   // 8 bf16 (4 VGPRs)
typedef __attribute__((ext_vector_type(4))) float f32x4;
typedef __attribute__((ext_vector_type(4))) unsigned short ushort4v;
typedef __attribute__((ext_vector_type(4))) unsigned int uint4v;

__device__ __forceinline__ unsigned short f2bf(float x) {
  unsigned int u = __builtin_bit_cast(unsigned int, x);
  unsigned int r = u + 0x7FFFu + ((u >> 16) & 1u);   // RNE
  return (unsigned short)(r >> 16);
}
__device__ __forceinline__ float bf2f(unsigned short h) {
  unsigned int u = ((unsigned int)h) << 16;
  return __builtin_bit_cast(float, u);
}

// Row permutation (within each head): stored row s <-> true n.
//   s = 32j + 16t + 4g + r   <->   n = 32j + 8g + 4t + r
// GEMM1's MFMA output (rows s) then lands exactly in GEMM2's B-operand layout.

// ---------- precompute: A_bar (PERMUTED layout) and coef=(A_bar-1)/A (natural) ----------
__global__ void pc_params(const float* __restrict__ logdt,
                          const float* __restrict__ arelog,
                          const float* __restrict__ aim,
                          float* __restrict__ abr, float* __restrict__ abi,
                          float* __restrict__ cre, float* __restrict__ cim) {
  int i = blockIdx.x * 256 + threadIdx.x;            // i = h*256 + n (natural)
  float ld = logdt[i];
  float dt = log1pf(expf(ld));                       // softplus
  float Ar = -expf(arelog[i]);
  float Ai = aim[i];
  float e  = expf(dt * Ar);
  float th = dt * Ai;
  float Abr = e * cosf(th), Abi = e * sinf(th);
  int n = i & 255, h = i >> 8;
  // inverse permutation: n -> s
  int s = (n & ~31) + ((n >> 2) & 1) * 16 + ((n >> 3) & 3) * 4 + (n & 3);
  abr[h * 256 + s] = Abr; abi[h * 256 + s] = Abi;
  float den = Ar * Ar + Ai * Ai;
  float br = Abr - 1.0f;
  cre[i] = (br * Ar + Abi * Ai) / den;
  cim[i] = (Abi * Ar - br * Ai) / den;
}

// ---------- W1 = coef * B  (bf16, PERMUTED rows, layout (H, s, P)) ----------
__global__ void pc_w1(const float* __restrict__ Bre, const float* __restrict__ Bim,
                      const float* __restrict__ cre, const float* __restrict__ cim,
                      unsigned short* __restrict__ w1re, unsigned short* __restrict__ w1im) {
  int i = blockIdx.x * 256 + threadIdx.x;            // stored flat idx: h*32768 + s*128 + p
  int p = i & 127, s = (i >> 7) & 255, h = i >> 15;
  int kk = s >> 4, u = s & 15;
  int n = ((kk >> 1) << 5) + ((u >> 2) & 3) * 8 + (kk & 1) * 4 + (u & 3);
  int src = (h * 256 + n) * 128 + p;
  int hn = h * 256 + n;
  float cr = cre[hn], ci = cim[hn];
  float br = Bre[src], bi = Bim[src];
  w1re[i] = f2bf(cr * br - ci * bi);
  w1im[i] = f2bf(cr * bi + ci * br);
}

// ---------- W2 = C_re, -C_im  (bf16, natural layout (H,P,N)) ----------
__global__ void pc_w2(const float* __restrict__ Cre, const float* __restrict__ Cim,
                      unsigned short* __restrict__ w2re, unsigned short* __restrict__ w2mi) {
  int i = blockIdx.x * 256 + threadIdx.x;            // 262144 = H*P*N
  w2re[i] = f2bf(Cre[i]);
  w2mi[i] = f2bf(-Cim[i]);
}

// ---------- RMSNorm -> x_hat bf16 (one wave per row) ----------
__global__ __launch_bounds__(256) void rms_k(const float* __restrict__ xt,
                                             const float* __restrict__ w,
                                             unsigned short* __restrict__ xbf) {
  int wid = threadIdx.x >> 6, lane = threadIdx.x & 63;
  int row = blockIdx.x * 4 + wid;
  const float* xr = xt + (long)row * DIM;
  f32x4 v[4];
  float ssq = 0.f;
  #pragma unroll
  for (int c = 0; c < 4; ++c) {
    v[c] = *(const f32x4*)(xr + c * 256 + lane * 4);
    ssq += v[c][0]*v[c][0] + v[c][1]*v[c][1] + v[c][2]*v[c][2] + v[c][3]*v[c][3];
  }
  #pragma unroll
  for (int m = 1; m < 64; m <<= 1) ssq += __shfl_xor(ssq, m, 64);
  float sc = rsqrtf(ssq * (1.0f / DIM) + 1e-4f);
  unsigned short* orow = xbf + (long)row * DIM;
  #pragma unroll
  for (int c = 0; c < 4; ++c) {
    f32x4 w4 = *(const f32x4*)(w + c * 256 + lane * 4);
    ushort4v o;
    o[0] = f2bf(v[c][0] * sc * w4[0]);
    o[1] = f2bf(v[c][1] * sc * w4[1]);
    o[2] = f2bf(v[c][2] * sc * w4[2]);
    o[3] = f2bf(v[c][3] * sc * w4[3]);
    *(ushort4v*)(orow + c * 256 + lane * 4) = o;
  }
}

// ---------- main fused kernel: no LDS, no barriers, permuted-W1 trick ----------
// Grid: 1024 blocks = 128 x 8 heads, 256 threads = 4 waves.
// Each wave: 16 batch rows x 1 head, ALL 256 states (16 chunks of 16), all 128 p.
// Per 16-state chunk kk: GEMM1 (8 MFMA) -> recurrence -> pack bf16; every 2 chunks
// the packed P fragments are exactly GEMM2's B-operand (row permutation guarantees
// it) -> GEMM2 (16 MFMA) accumulates. State prefetched 2 chunks ahead through a
// 4-slot circular register buffer (static indices under full unroll).
__global__ __launch_bounds__(256, 3) void s5_main(
    const unsigned short* __restrict__ xbf,
    const unsigned short* __restrict__ w1re, const unsigned short* __restrict__ w1im,
    const unsigned short* __restrict__ w2re, const unsigned short* __restrict__ w2mi,
    const float* __restrict__ abrp, const float* __restrict__ abip,
    const float* __restrict__ sre, const float* __restrict__ sim,
    const float* __restrict__ xt, const float* __restrict__ dvec,
    float* __restrict__ out, float* __restrict__ nsre, float* __restrict__ nsim) {
  const int tid = threadIdx.x;
  const int wid = tid >> 6, lane = tid & 63;
  const int g = lane >> 4, bl = lane & 15;
  const int h = blockIdx.x & 7;
  const int b = (blockIdx.x >> 3) * 64 + wid * 16 + bl;

  // x_hat B-fragments (GEMM1): lane (g,bl): col b, k = p = ks*32 + g*8 + e
  short8v xf[4];
  {
    const unsigned short* xrow = xbf + (size_t)b * DIM + h * HEAD_DIM + g * 8;
    #pragma unroll
    for (int ks = 0; ks < 4; ++ks)
      xf[ks] = *(const short8v*)(xrow + ks * 32);
  }

  const size_t sbase = ((size_t)b * HEADS + h) * DSTATE;
  // true-n offset of this lane's 4 recurrence elements for chunk kk:
  //   noff(kk) = (kk>>1)*32 + g*8 + (kk&1)*4
  f32x4 sr[4], si[4];          // 4-slot circular prefetch buffer
  {
    sr[0] = *(const f32x4*)(sre + sbase + g * 8);
    si[0] = *(const f32x4*)(sim + sbase + g * 8);
    sr[1] = *(const f32x4*)(sre + sbase + g * 8 + 4);
    si[1] = *(const f32x4*)(sim + sbase + g * 8 + 4);
  }

  f32x4 acc[8];
  #pragma unroll
  for (int pt = 0; pt < 8; ++pt) { f32x4 z = {0.f,0.f,0.f,0.f}; acc[pt] = z; }

  unsigned prLo = 0, prHi = 0, piLo = 0, piHi = 0;   // even-chunk packed halves

  #pragma unroll
  for (int kk = 0; kk < 16; ++kk) {
    // prefetch state 2 chunks ahead into circular slot
    if (kk + 2 < 16) {
      const int no2 = (((kk + 2) >> 1) << 5) + g * 8 + (((kk + 2) & 1) << 2);
      sr[(kk + 2) & 3] = *(const f32x4*)(sre + sbase + no2);
      si[(kk + 2) & 3] = *(const f32x4*)(sim + sbase + no2);
    }
    // W1 fragments for chunk kk (permuted rows): A-operand row bl -> s=kk*16+bl
    const unsigned short* w1b = w1re + ((size_t)(h * DSTATE + kk * 16 + bl)) * HEAD_DIM + g * 8;
    const unsigned short* w1c = w1im + ((size_t)(h * DSTATE + kk * 16 + bl)) * HEAD_DIM + g * 8;
    f32x4 dr = {0.f,0.f,0.f,0.f};
    f32x4 di = {0.f,0.f,0.f,0.f};
    #pragma unroll
    for (int ks = 0; ks < 4; ++ks) {
      short8v ar = *(const short8v*)(w1b + ks * 32);
      dr = __builtin_amdgcn_mfma_f32_16x16x32_bf16(ar, xf[ks], dr, 0, 0, 0);
    }
    #pragma unroll
    for (int ks = 0; ks < 4; ++ks) {
      short8v ai = *(const short8v*)(w1c + ks * 32);
      di = __builtin_amdgcn_mfma_f32_16x16x32_bf16(ai, xf[ks], di, 0, 0, 0);
    }
    // recurrence: ns = A_bar * state + Bx   (A_bar stored pre-permuted)
    const f32x4 Ar = *(const f32x4*)(abrp + h * DSTATE + kk * 16 + g * 4);
    const f32x4 Ai = *(const f32x4*)(abip + h * DSTATE + kk * 16 + g * 4);
    f32x4 nr, ni;
    #pragma unroll
    for (int r = 0; r < 4; ++r) {
      nr[r] = fmaf(Ar[r], sr[kk & 3][r], fmaf(-Ai[r], si[kk & 3][r], dr[r]));
      ni[r] = fmaf(Ar[r], si[kk & 3][r], fmaf(Ai[r], sr[kk & 3][r], di[r]));
    }
    const int no = ((kk >> 1) << 5) + g * 8 + ((kk & 1) << 2);
    *(f32x4*)(nsre + sbase + no) = nr;
    *(f32x4*)(nsim + sbase + no) = ni;
    // pack to bf16 (these 4 values are B-frag elements e = (kk&1)*4 + {0..3})
    unsigned lo = (unsigned)f2bf(nr[0]) | ((unsigned)f2bf(nr[1]) << 16);
    unsigned hi = (unsigned)f2bf(nr[2]) | ((unsigned)f2bf(nr[3]) << 16);
    unsigned lo2 = (unsigned)f2bf(ni[0]) | ((unsigned)f2bf(ni[1]) << 16);
    unsigned hi2 = (unsigned)f2bf(ni[2]) | ((unsigned)f2bf(ni[3]) << 16);
    if ((kk & 1) == 0) {
      prLo = lo; prHi = hi; piLo = lo2; piHi = hi2;
    } else {
      const int j = kk >> 1;                       // K-window of 32 states
      uint4v urv; urv[0] = prLo; urv[1] = prHi; urv[2] = lo; urv[3] = hi;
      uint4v uiv; uiv[0] = piLo; uiv[1] = piHi; uiv[2] = lo2; uiv[3] = hi2;
      short8v pbr = __builtin_bit_cast(short8v, urv);
      short8v pbi = __builtin_bit_cast(short8v, uiv);
      const unsigned short* w2rb = w2re + ((size_t)(h * HEAD_DIM + bl)) * DSTATE + j * 32 + g * 8;
      const unsigned short* w2ib = w2mi + ((size_t)(h * HEAD_DIM + bl)) * DSTATE + j * 32 + g * 8;
      #pragma unroll
      for (int pt = 0; pt < 8; ++pt) {
        short8v a2r = *(const short8v*)(w2rb + pt * 16 * DSTATE);
        short8v a2i = *(const short8v*)(w2ib + pt * 16 * DSTATE);
        acc[pt] = __builtin_amdgcn_mfma_f32_16x16x32_bf16(a2r, pbr, acc[pt], 0, 0, 0);
        acc[pt] = __builtin_amdgcn_mfma_f32_16x16x32_bf16(a2i, pbi, acc[pt], 0, 0, 0);
      }
    }
  }

  // epilogue: out = x_t + 2*Ch + D*x_hat ; acc row = p-within-tile, col = b
  #pragma unroll
  for (int pt = 0; pt < 8; ++pt) {
    const int col = h * HEAD_DIM + pt * 16 + g * 4;
    const size_t o = (size_t)b * DIM + col;
    const f32x4 xt4 = *(const f32x4*)(xt + o);
    const f32x4 d4 = *(const f32x4*)(dvec + col);
    ushort4v xh4 = *(const ushort4v*)(xbf + o);
    f32x4 ro;
    #pragma unroll
    for (int r = 0; r < 4; ++r)
      ro[r] = xt4[r] + 2.0f * acc[pt][r] + d4[r] * bf2f(xh4[r]);
    *(f32x4*)(out + o) = ro;
  }
}

extern "C" void kernel_launch(void* const* d_in, const int* in_sizes, int n_in,
                              void* d_out, int out_size, void* d_ws, size_t ws_size,
                              hipStream_t stream) {
  const float* x_t      = (const float*)d_in[0];
  const float* state_re = (const float*)d_in[1];
  const float* state_im = (const float*)d_in[2];
  const float* norm_w   = (const float*)d_in[3];
  const float* A_re_log = (const float*)d_in[4];
  const float* A_im     = (const float*)d_in[5];
  const float* B_re     = (const float*)d_in[6];
  const float* B_im     = (const float*)d_in[7];
  const float* C_re     = (const float*)d_in[8];
  const float* C_im     = (const float*)d_in[9];
  const float* Dv       = (const float*)d_in[10];
  const float* log_dt   = (const float*)d_in[11];

  float* out   = (float*)d_out;
  float* ns_re = out + (size_t)BATCH * DIM;
  float* ns_im = ns_re + (size_t)BATCH * HEADS * DSTATE;

  char* ws = (char*)d_ws;
  unsigned short* xbf  = (unsigned short*)ws;                       // 16 MB
  unsigned short* w1re = (unsigned short*)(ws + 16777216);          // 512 KB each
  unsigned short* w1im = w1re + 262144;
  unsigned short* w2re = w1im + 262144;
  unsigned short* w2mi = w2re + 262144;
  float* abr = (float*)(ws + 16777216 + 4 * 524288);
  float* abi = abr + 2048;
  float* cre = abi + 2048;
  float* cim = cre + 2048;

  pc_params<<<8, 256, 0, stream>>>(log_dt, A_re_log, A_im, abr, abi, cre, cim);
  pc_w1<<<1024, 256, 0, stream>>>(B_re, B_im, cre, cim, w1re, w1im);
  pc_w2<<<1024, 256, 0, stream>>>(C_re, C_im, w2re, w2mi);
  rms_k<<<2048, 256, 0, stream>>>(x_t, norm_w, xbf);
  s5_main<<<1024, 256, 0, stream>>>(xbf, w1re, w1im, w2re, w2mi, abr, abi,
                                    state_re, state_im, x_t, Dv, out, ns_re, ns_im);
}

// Round 6
// 183.190 us; speedup vs baseline: 1.3217x; 1.3217x over previous
//
#include <hip/hip_runtime.h>

#define BATCH 8192
#define DIM 1024
#define HEADS 8
#define HEAD_DIM 128
#define DSTATE 256

typedef __attribute__((ext_vector_type(8))) short short8v;   // 8 bf16 (4 VGPRs)
typedef __attribute__((ext_vector_type(4))) float f32x4;
typedef __attribute__((ext_vector_type(4))) unsigned short ushort4v;
typedef __attribute__((ext_vector_type(4))) unsigned int uint4v;

__device__ __forceinline__ unsigned short f2bf(float x) {
  unsigned int u = __builtin_bit_cast(unsigned int, x);
  unsigned int r = u + 0x7FFFu + ((u >> 16) & 1u);   // RNE
  return (unsigned short)(r >> 16);
}
__device__ __forceinline__ float bf2f(unsigned short h) {
  unsigned int u = ((unsigned int)h) << 16;
  return __builtin_bit_cast(float, u);
}

// Row permutation (within each head): stored row s <-> true n.
//   s = 32j + 16t + 4g + r   <->   n = 32j + 8g + 4t + r
// GEMM1's MFMA output (rows s) then lands exactly in GEMM2's B-operand layout.

// ---------- precompute: A_bar (PERMUTED layout) and coef=(A_bar-1)/A (natural) ----------
__global__ void pc_params(const float* __restrict__ logdt,
                          const float* __restrict__ arelog,
                          const float* __restrict__ aim,
                          float* __restrict__ abr, float* __restrict__ abi,
                          float* __restrict__ cre, float* __restrict__ cim) {
  int i = blockIdx.x * 256 + threadIdx.x;            // i = h*256 + n (natural)
  float ld = logdt[i];
  float dt = log1pf(expf(ld));                       // softplus
  float Ar = -expf(arelog[i]);
  float Ai = aim[i];
  float e  = expf(dt * Ar);
  float th = dt * Ai;
  float Abr = e * cosf(th), Abi = e * sinf(th);
  int n = i & 255, h = i >> 8;
  // inverse permutation: n -> s
  int s = (n & ~31) + ((n >> 2) & 1) * 16 + ((n >> 3) & 3) * 4 + (n & 3);
  abr[h * 256 + s] = Abr; abi[h * 256 + s] = Abi;
  float den = Ar * Ar + Ai * Ai;
  float br = Abr - 1.0f;
  cre[i] = (br * Ar + Abi * Ai) / den;
  cim[i] = (Abi * Ar - br * Ai) / den;
}

// ---------- W1 = coef * B  (bf16, PERMUTED rows, layout (H, s, P)) ----------
__global__ void pc_w1(const float* __restrict__ Bre, const float* __restrict__ Bim,
                      const float* __restrict__ cre, const float* __restrict__ cim,
                      unsigned short* __restrict__ w1re, unsigned short* __restrict__ w1im) {
  int i = blockIdx.x * 256 + threadIdx.x;            // stored flat idx: h*32768 + s*128 + p
  int p = i & 127, s = (i >> 7) & 255, h = i >> 15;
  int kk = s >> 4, u = s & 15;
  int n = ((kk >> 1) << 5) + ((u >> 2) & 3) * 8 + (kk & 1) * 4 + (u & 3);
  int src = (h * 256 + n) * 128 + p;
  int hn = h * 256 + n;
  float cr = cre[hn], ci = cim[hn];
  float br = Bre[src], bi = Bim[src];
  w1re[i] = f2bf(cr * br - ci * bi);
  w1im[i] = f2bf(cr * bi + ci * br);
}

// ---------- W2 = C_re, -C_im  (bf16, natural layout (H,P,N)) ----------
__global__ void pc_w2(const float* __restrict__ Cre, const float* __restrict__ Cim,
                      unsigned short* __restrict__ w2re, unsigned short* __restrict__ w2mi) {
  int i = blockIdx.x * 256 + threadIdx.x;            // 262144 = H*P*N
  w2re[i] = f2bf(Cre[i]);
  w2mi[i] = f2bf(-Cim[i]);
}

// ---------- RMSNorm -> x_hat bf16 (one wave per row) ----------
__global__ __launch_bounds__(256) void rms_k(const float* __restrict__ xt,
                                             const float* __restrict__ w,
                                             unsigned short* __restrict__ xbf) {
  int wid = threadIdx.x >> 6, lane = threadIdx.x & 63;
  int row = blockIdx.x * 4 + wid;
  const float* xr = xt + (long)row * DIM;
  f32x4 v[4];
  float ssq = 0.f;
  #pragma unroll
  for (int c = 0; c < 4; ++c) {
    v[c] = *(const f32x4*)(xr + c * 256 + lane * 4);
    ssq += v[c][0]*v[c][0] + v[c][1]*v[c][1] + v[c][2]*v[c][2] + v[c][3]*v[c][3];
  }
  #pragma unroll
  for (int m = 1; m < 64; m <<= 1) ssq += __shfl_xor(ssq, m, 64);
  float sc = rsqrtf(ssq * (1.0f / DIM) + 1e-4f);
  unsigned short* orow = xbf + (long)row * DIM;
  #pragma unroll
  for (int c = 0; c < 4; ++c) {
    f32x4 w4 = *(const f32x4*)(w + c * 256 + lane * 4);
    ushort4v o;
    o[0] = f2bf(v[c][0] * sc * w4[0]);
    o[1] = f2bf(v[c][1] * sc * w4[1]);
    o[2] = f2bf(v[c][2] * sc * w4[2]);
    o[3] = f2bf(v[c][3] * sc * w4[3]);
    *(ushort4v*)(orow + c * 256 + lane * 4) = o;
  }
}

// ---------- main fused kernel: no LDS/barriers, permuted-W1, bt=2 ILP ----------
// Grid: 512 blocks = 64 x 8 heads, 256 threads = 4 waves.
// Each wave: TWO independent 16-row tiles x 1 head (2x ILP, weight loads
// amortized). Window j (32 states): GEMM1 chunks t=0,1 -> recurrence ->
// paired CONTIGUOUS ns writes (32B/lane, no sector amp) -> GEMM2 accumulate.
// State for window j+1 double-buffer-prefetched during window j.
__global__ __launch_bounds__(256, 2) void s5_main(
    const unsigned short* __restrict__ xbf,
    const unsigned short* __restrict__ w1re, const unsigned short* __restrict__ w1im,
    const unsigned short* __restrict__ w2re, const unsigned short* __restrict__ w2mi,
    const float* __restrict__ abrp, const float* __restrict__ abip,
    const float* __restrict__ sre, const float* __restrict__ sim,
    const float* __restrict__ xt, const float* __restrict__ dvec,
    float* __restrict__ out, float* __restrict__ nsre, float* __restrict__ nsim) {
  const int tid = threadIdx.x;
  const int wid = tid >> 6, lane = tid & 63;
  const int g = lane >> 4, bl = lane & 15;
  const int h = blockIdx.x & 7;
  const int rowbase = (blockIdx.x >> 3) * 128 + wid * 32;

  size_t sbase[2];
  sbase[0] = (((size_t)(rowbase + bl)) * HEADS + h) * DSTATE;
  sbase[1] = (((size_t)(rowbase + 16 + bl)) * HEADS + h) * DSTATE;

  // x_hat B-fragments (GEMM1): lane (g,bl): col b, k = p = ks*32 + g*8 + e
  short8v xf[2][4];
  #pragma unroll
  for (int bt = 0; bt < 2; ++bt) {
    const unsigned short* xrow = xbf + (size_t)(rowbase + bt * 16 + bl) * DIM + h * HEAD_DIM + g * 8;
    #pragma unroll
    for (int ks = 0; ks < 4; ++ks)
      xf[bt][ks] = *(const short8v*)(xrow + ks * 32);
  }

  // state double-buffer: [buf][bt][t]  (t: n-offset 32j+8g+4t)
  f32x4 stR[2][2][2], stI[2][2][2];
  #pragma unroll
  for (int bt = 0; bt < 2; ++bt) {
    stR[0][bt][0] = *(const f32x4*)(sre + sbase[bt] + g * 8);
    stR[0][bt][1] = *(const f32x4*)(sre + sbase[bt] + g * 8 + 4);
    stI[0][bt][0] = *(const f32x4*)(sim + sbase[bt] + g * 8);
    stI[0][bt][1] = *(const f32x4*)(sim + sbase[bt] + g * 8 + 4);
  }

  f32x4 acc[8][2];
  #pragma unroll
  for (int pt = 0; pt < 8; ++pt) {
    f32x4 z = {0.f,0.f,0.f,0.f};
    acc[pt][0] = z; acc[pt][1] = z;
  }

  #pragma unroll
  for (int j = 0; j < 8; ++j) {
    const int cb = j & 1, nb = cb ^ 1;
    // prefetch next window's state (one full window of latency slack)
    if (j < 7) {
      const int no = (j + 1) * 32 + g * 8;
      #pragma unroll
      for (int bt = 0; bt < 2; ++bt) {
        stR[nb][bt][0] = *(const f32x4*)(sre + sbase[bt] + no);
        stR[nb][bt][1] = *(const f32x4*)(sre + sbase[bt] + no + 4);
        stI[nb][bt][0] = *(const f32x4*)(sim + sbase[bt] + no);
        stI[nb][bt][1] = *(const f32x4*)(sim + sbase[bt] + no + 4);
      }
    }

    f32x4 nrs[2][2], nis[2][2];                      // [bt][t]
    unsigned pr0[2], pr1[2], pi0[2], pi1[2];
    short8v pbr[2], pbi[2];

    #pragma unroll
    for (int t = 0; t < 2; ++t) {
      const int kk = 2 * j + t;
      const unsigned short* w1b = w1re + ((size_t)(h * DSTATE + kk * 16 + bl)) * HEAD_DIM + g * 8;
      const unsigned short* w1c = w1im + ((size_t)(h * DSTATE + kk * 16 + bl)) * HEAD_DIM + g * 8;
      short8v ar0 = *(const short8v*)(w1b);
      short8v ar1 = *(const short8v*)(w1b + 32);
      short8v ar2 = *(const short8v*)(w1b + 64);
      short8v ar3 = *(const short8v*)(w1b + 96);
      short8v ai0 = *(const short8v*)(w1c);
      short8v ai1 = *(const short8v*)(w1c + 32);
      short8v ai2 = *(const short8v*)(w1c + 64);
      short8v ai3 = *(const short8v*)(w1c + 96);
      const f32x4 Ar = *(const f32x4*)(abrp + h * DSTATE + kk * 16 + g * 4);
      const f32x4 Ai = *(const f32x4*)(abip + h * DSTATE + kk * 16 + g * 4);
      #pragma unroll
      for (int bt = 0; bt < 2; ++bt) {
        f32x4 dr = {0.f,0.f,0.f,0.f};
        f32x4 di = {0.f,0.f,0.f,0.f};
        dr = __builtin_amdgcn_mfma_f32_16x16x32_bf16(ar0, xf[bt][0], dr, 0, 0, 0);
        dr = __builtin_amdgcn_mfma_f32_16x16x32_bf16(ar1, xf[bt][1], dr, 0, 0, 0);
        dr = __builtin_amdgcn_mfma_f32_16x16x32_bf16(ar2, xf[bt][2], dr, 0, 0, 0);
        dr = __builtin_amdgcn_mfma_f32_16x16x32_bf16(ar3, xf[bt][3], dr, 0, 0, 0);
        di = __builtin_amdgcn_mfma_f32_16x16x32_bf16(ai0, xf[bt][0], di, 0, 0, 0);
        di = __builtin_amdgcn_mfma_f32_16x16x32_bf16(ai1, xf[bt][1], di, 0, 0, 0);
        di = __builtin_amdgcn_mfma_f32_16x16x32_bf16(ai2, xf[bt][2], di, 0, 0, 0);
        di = __builtin_amdgcn_mfma_f32_16x16x32_bf16(ai3, xf[bt][3], di, 0, 0, 0);
        f32x4 nr, ni;
        #pragma unroll
        for (int r = 0; r < 4; ++r) {
          nr[r] = fmaf(Ar[r], stR[cb][bt][t][r], fmaf(-Ai[r], stI[cb][bt][t][r], dr[r]));
          ni[r] = fmaf(Ar[r], stI[cb][bt][t][r], fmaf(Ai[r], stR[cb][bt][t][r], di[r]));
        }
        nrs[bt][t] = nr; nis[bt][t] = ni;
        unsigned lo  = (unsigned)f2bf(nr[0]) | ((unsigned)f2bf(nr[1]) << 16);
        unsigned hi  = (unsigned)f2bf(nr[2]) | ((unsigned)f2bf(nr[3]) << 16);
        unsigned lo2 = (unsigned)f2bf(ni[0]) | ((unsigned)f2bf(ni[1]) << 16);
        unsigned hi2 = (unsigned)f2bf(ni[2]) | ((unsigned)f2bf(ni[3]) << 16);
        if (t == 0) {
          pr0[bt] = lo; pr1[bt] = hi; pi0[bt] = lo2; pi1[bt] = hi2;
        } else {
          uint4v urv; urv[0] = pr0[bt]; urv[1] = pr1[bt]; urv[2] = lo;  urv[3] = hi;
          uint4v uiv; uiv[0] = pi0[bt]; uiv[1] = pi1[bt]; uiv[2] = lo2; uiv[3] = hi2;
          pbr[bt] = __builtin_bit_cast(short8v, urv);
          pbi[bt] = __builtin_bit_cast(short8v, uiv);
        }
      }
    }

    // paired CONTIGUOUS ns writes: 32B per lane per stream, full sectors
    #pragma unroll
    for (int bt = 0; bt < 2; ++bt) {
      const size_t no = sbase[bt] + j * 32 + g * 8;
      *(f32x4*)(nsre + no)     = nrs[bt][0];
      *(f32x4*)(nsre + no + 4) = nrs[bt][1];
      *(f32x4*)(nsim + no)     = nis[bt][0];
      *(f32x4*)(nsim + no + 4) = nis[bt][1];
    }

    // GEMM2 partial over this 32-state window
    const unsigned short* w2rb = w2re + ((size_t)(h * HEAD_DIM + bl)) * DSTATE + j * 32 + g * 8;
    const unsigned short* w2ib = w2mi + ((size_t)(h * HEAD_DIM + bl)) * DSTATE + j * 32 + g * 8;
    #pragma unroll
    for (int pt = 0; pt < 8; ++pt) {
      short8v a2r = *(const short8v*)(w2rb + pt * 16 * DSTATE);
      short8v a2i = *(const short8v*)(w2ib + pt * 16 * DSTATE);
      #pragma unroll
      for (int bt = 0; bt < 2; ++bt) {
        acc[pt][bt] = __builtin_amdgcn_mfma_f32_16x16x32_bf16(a2r, pbr[bt], acc[pt][bt], 0, 0, 0);
        acc[pt][bt] = __builtin_amdgcn_mfma_f32_16x16x32_bf16(a2i, pbi[bt], acc[pt][bt], 0, 0, 0);
      }
    }
  }

  // epilogue: out = x_t + 2*Ch + D*x_hat ; acc row = p-within-tile, col = b
  #pragma unroll
  for (int pt = 0; pt < 8; ++pt) {
    #pragma unroll
    for (int bt = 0; bt < 2; ++bt) {
      const int col = h * HEAD_DIM + pt * 16 + g * 4;
      const size_t o = (size_t)(rowbase + bt * 16 + bl) * DIM + col;
      const f32x4 xt4 = *(const f32x4*)(xt + o);
      const f32x4 d4 = *(const f32x4*)(dvec + col);
      ushort4v xh4 = *(const ushort4v*)(xbf + o);
      f32x4 ro;
      #pragma unroll
      for (int r = 0; r < 4; ++r)
        ro[r] = xt4[r] + 2.0f * acc[pt][bt][r] + d4[r] * bf2f(xh4[r]);
      *(f32x4*)(out + o) = ro;
    }
  }
}

extern "C" void kernel_launch(void* const* d_in, const int* in_sizes, int n_in,
                              void* d_out, int out_size, void* d_ws, size_t ws_size,
                              hipStream_t stream) {
  const float* x_t      = (const float*)d_in[0];
  const float* state_re = (const float*)d_in[1];
  const float* state_im = (const float*)d_in[2];
  const float* norm_w   = (const float*)d_in[3];
  const float* A_re_log = (const float*)d_in[4];
  const float* A_im     = (const float*)d_in[5];
  const float* B_re     = (const float*)d_in[6];
  const float* B_im     = (const float*)d_in[7];
  const float* C_re     = (const float*)d_in[8];
  const float* C_im     = (const float*)d_in[9];
  const float* Dv       = (const float*)d_in[10];
  const float* log_dt   = (const float*)d_in[11];

  float* out   = (float*)d_out;
  float* ns_re = out + (size_t)BATCH * DIM;
  float* ns_im = ns_re + (size_t)BATCH * HEADS * DSTATE;

  char* ws = (char*)d_ws;
  unsigned short* xbf  = (unsigned short*)ws;                       // 16 MB
  unsigned short* w1re = (unsigned short*)(ws + 16777216);          // 512 KB each
  unsigned short* w1im = w1re + 262144;
  unsigned short* w2re = w1im + 262144;
  unsigned short* w2mi = w2re + 262144;
  float* abr = (float*)(ws + 16777216 + 4 * 524288);
  float* abi = abr + 2048;
  float* cre = abi + 2048;
  float* cim = cre + 2048;

  pc_params<<<8, 256, 0, stream>>>(log_dt, A_re_log, A_im, abr, abi, cre, cim);
  pc_w1<<<1024, 256, 0, stream>>>(B_re, B_im, cre, cim, w1re, w1im);
  pc_w2<<<1024, 256, 0, stream>>>(C_re, C_im, w2re, w2mi);
  rms_k<<<2048, 256, 0, stream>>>(x_t, norm_w, xbf);
  s5_main<<<512, 256, 0, stream>>>(xbf, w1re, w1im, w2re, w2mi, abr, abi,
                                   state_re, state_im, x_t, Dv, out, ns_re, ns_im);
}